// Round 1
// baseline (166.363 us; speedup 1.0000x reference)
//
#include <hip/hip_runtime.h>

#define B 8
#define T 2048
#define D 256
#define L 8
#define E 64
#define BT (B*T)
#define TC 8

// workspace layout (float offsets)
#define OFF_I  0
#define OFF_F  (OFF_I + B*L*T)
#define OFF_W  (OFF_F + B*L*T)
#define OFF_V  (OFF_W + B*L*T)
#define OFF_K  (OFF_V + B*L*T*E)
#define OFF_CP (OFF_K + B*L*T*E)
#define OFF_NP (OFF_CP + B*L*TC*E*E)

// ---------------------------------------------------------------------------
// K1: i/f gate projections.  lg = x @ W_lin^T + b_lin  -> ibuf/fbuf (B,L,T)
// ---------------------------------------------------------------------------
__global__ __launch_bounds__(256) void k_ifproj(const float* __restrict__ x,
        const float* __restrict__ Wlin, const float* __restrict__ blin,
        float* __restrict__ ibuf, float* __restrict__ fbuf) {
    __shared__ float xs[32][260];
    __shared__ float ws[16][260];
    int tid = threadIdx.x;
    int t0 = blockIdx.x * 32;
    {
        int row = tid >> 3, q = tid & 7;
        const float* src = x + (size_t)(t0 + row) * D + q * 32;
        #pragma unroll
        for (int j = 0; j < 8; ++j) {
            float4 v = *(const float4*)(src + j * 4);
            *(float4*)&xs[row][q * 32 + j * 4] = v;
        }
    }
    {
        int row = tid >> 4, c0 = (tid & 15) * 16;
        const float* src = Wlin + row * D + c0;
        #pragma unroll
        for (int j = 0; j < 4; ++j) {
            float4 v = *(const float4*)(src + j * 4);
            *(float4*)&ws[row][c0 + j * 4] = v;
        }
    }
    __syncthreads();
    int tl = tid >> 4, g = tid & 15;
    float acc0 = 0.f, acc1 = 0.f;
    for (int i = 0; i < D; ++i) {
        float wv = ws[g][i];
        acc0 += xs[tl * 2 + 0][i] * wv;
        acc1 += xs[tl * 2 + 1][i] * wv;
    }
    float bias = blin[g];
    float acc[2] = {acc0 + bias, acc1 + bias};
    #pragma unroll
    for (int u = 0; u < 2; ++u) {
        int t = t0 + tl * 2 + u;
        int b = t >> 11, tt = t & 2047;
        if (g < 8) ibuf[(b * L + g) * T + tt] = acc[u];
        else       fbuf[(b * L + (g - 8)) * T + tt] = acc[u];
    }
}

// ---------------------------------------------------------------------------
// K2: per-(b,l) scan.  S_t = cumsum(f), e_t = i_t - S_t, M = max(0, max e_t),
//     w_t = exp(e_t - M).  One block per (b,l).
// ---------------------------------------------------------------------------
__global__ __launch_bounds__(256) void k_scan(const float* __restrict__ ibuf,
        const float* __restrict__ fbuf, float* __restrict__ wbuf) {
    __shared__ float part[256];
    __shared__ float red[256];
    int tid = threadIdx.x;
    int base = blockIdx.x * T;
    const float* fp = fbuf + base + tid * 8;
    const float* ip = ibuf + base + tid * 8;
    float4 fa = *(const float4*)fp;
    float4 fb = *(const float4*)(fp + 4);
    float4 ia = *(const float4*)ip;
    float4 ib = *(const float4*)(ip + 4);
    float f[8] = {fa.x, fa.y, fa.z, fa.w, fb.x, fb.y, fb.z, fb.w};
    float iv[8] = {ia.x, ia.y, ia.z, ia.w, ib.x, ib.y, ib.z, ib.w};
    float ls[8]; float run = 0.f;
    #pragma unroll
    for (int r = 0; r < 8; ++r) { run += f[r]; ls[r] = run; }
    part[tid] = run;
    __syncthreads();
    if (tid == 0) {
        float running = 0.f;
        for (int k = 0; k < 256; ++k) { float tmp = part[k]; part[k] = running; running += tmp; }
    }
    __syncthreads();
    float off = part[tid];
    float e[8]; float lmax = -1e30f;
    #pragma unroll
    for (int r = 0; r < 8; ++r) { e[r] = iv[r] - (off + ls[r]); lmax = fmaxf(lmax, e[r]); }
    red[tid] = lmax;
    __syncthreads();
    for (int s = 128; s > 0; s >>= 1) {
        if (tid < s) red[tid] = fmaxf(red[tid], red[tid + s]);
        __syncthreads();
    }
    float M = fmaxf(red[0], 0.0f);
    float w[8];
    #pragma unroll
    for (int r = 0; r < 8; ++r) w[r] = __expf(e[r] - M);
    float4 wa = {w[0], w[1], w[2], w[3]};
    float4 wb = {w[4], w[5], w[6], w[7]};
    float* wp = wbuf + base + tid * 8;
    *(float4*)wp = wa;
    *(float4*)(wp + 4) = wb;
}

// ---------------------------------------------------------------------------
// K3: v,k projections.  GEMM (BT,256) x (256, 2*L*E) -> V,K buffers (B,L,T,E).
// grid (BT/64, 16): by -> (l, vk).  64x64 output tile, K=256 in 4 chunks.
// ---------------------------------------------------------------------------
__global__ __launch_bounds__(256) void k_vkproj(const float* __restrict__ x,
        const float* __restrict__ Wml, const float* __restrict__ bml,
        float* __restrict__ Vbuf, float* __restrict__ Kbuf) {
    __shared__ float As[64][68];   // transposed: As[kk][m]
    __shared__ float Bs[64][68];   // Bs[kk][n]
    int tid = threadIdx.x;
    int bx = blockIdx.x;
    int by = blockIdx.y;
    int l = by >> 1, vk = by & 1;
    int wrow = (1 + vk) * L + l;
    int tx = tid & 15, ty = tid >> 4;
    int arow = tid >> 2, aq = tid & 3;
    float acc[4][4] = {};
    for (int kc = 0; kc < 4; ++kc) {
        int k0 = kc * 64;
        const float* asrc = x + (size_t)(bx * 64 + arow) * D + k0 + aq * 16;
        #pragma unroll
        for (int j = 0; j < 4; ++j) {
            float4 v = *(const float4*)(asrc + j * 4);
            int kk = aq * 16 + j * 4;
            As[kk + 0][arow] = v.x;
            As[kk + 1][arow] = v.y;
            As[kk + 2][arow] = v.z;
            As[kk + 3][arow] = v.w;
        }
        const float* bsrc = Wml + ((size_t)wrow * D + k0 + arow) * E + aq * 16;
        #pragma unroll
        for (int j = 0; j < 4; ++j) {
            float4 v = *(const float4*)(bsrc + j * 4);
            *(float4*)&Bs[arow][aq * 16 + j * 4] = v;
        }
        __syncthreads();
        #pragma unroll 8
        for (int kk = 0; kk < 64; ++kk) {
            float4 av = *(const float4*)&As[kk][ty * 4];
            float4 bv = *(const float4*)&Bs[kk][tx * 4];
            float a[4] = {av.x, av.y, av.z, av.w};
            float bb[4] = {bv.x, bv.y, bv.z, bv.w};
            #pragma unroll
            for (int r = 0; r < 4; ++r)
                #pragma unroll
                for (int c = 0; c < 4; ++c)
                    acc[r][c] += a[r] * bb[c];
        }
        __syncthreads();
    }
    float4 bias = *(const float4*)(bml + wrow * E + tx * 4);
    float bb[4] = {bias.x, bias.y, bias.z, bias.w};
    float* obuf = vk ? Kbuf : Vbuf;
    #pragma unroll
    for (int r = 0; r < 4; ++r) {
        int t = bx * 64 + ty * 4 + r;
        int b = t >> 11, tt = t & 2047;
        float4 o;
        o.x = acc[r][0] + bb[0]; o.y = acc[r][1] + bb[1];
        o.z = acc[r][2] + bb[2]; o.w = acc[r][3] + bb[3];
        *(float4*)(obuf + ((size_t)(b * L + l) * T + tt) * E + tx * 4) = o;
    }
}

// ---------------------------------------------------------------------------
// K4: weighted C-GEMM per (b,l): C = V^T diag(w) K over a 256-step t-chunk.
// grid (64, TC).  Also accumulates n_j = sum w_t k_t[j] partials.
// ---------------------------------------------------------------------------
__global__ __launch_bounds__(256) void k_cgemm(const float* __restrict__ Vbuf,
        const float* __restrict__ Kbuf, const float* __restrict__ wbuf,
        float* __restrict__ Cpart, float* __restrict__ npart) {
    __shared__ float Vs[32][68];
    __shared__ float Ks[32][68];   // weighted by w
    int tid = threadIdx.x;
    int bl = blockIdx.x;
    int tc = blockIdx.y;
    int t0 = tc * 256;
    int tx = tid & 15, ty = tid >> 4;
    int lrow = tid >> 3, lq = tid & 7;
    float acc[4][4] = {};
    float nacc = 0.0f;
    for (int c2 = 0; c2 < 8; ++c2) {
        int tb = t0 + c2 * 32;
        const float* vsrc = Vbuf + ((size_t)bl * T + tb + lrow) * E + lq * 8;
        const float* ksrc = Kbuf + ((size_t)bl * T + tb + lrow) * E + lq * 8;
        float wv = wbuf[bl * T + tb + lrow];
        float4 v0 = *(const float4*)(vsrc);
        float4 v1 = *(const float4*)(vsrc + 4);
        float4 k0 = *(const float4*)(ksrc);
        float4 k1 = *(const float4*)(ksrc + 4);
        k0.x *= wv; k0.y *= wv; k0.z *= wv; k0.w *= wv;
        k1.x *= wv; k1.y *= wv; k1.z *= wv; k1.w *= wv;
        *(float4*)&Vs[lrow][lq * 8] = v0;
        *(float4*)&Vs[lrow][lq * 8 + 4] = v1;
        *(float4*)&Ks[lrow][lq * 8] = k0;
        *(float4*)&Ks[lrow][lq * 8 + 4] = k1;
        __syncthreads();
        #pragma unroll 8
        for (int s = 0; s < 32; ++s) {
            float4 av = *(const float4*)&Vs[s][ty * 4];
            float4 bv = *(const float4*)&Ks[s][tx * 4];
            float a[4] = {av.x, av.y, av.z, av.w};
            float bb[4] = {bv.x, bv.y, bv.z, bv.w};
            #pragma unroll
            for (int r = 0; r < 4; ++r)
                #pragma unroll
                for (int c = 0; c < 4; ++c)
                    acc[r][c] += a[r] * bb[c];
        }
        if (tid < 64) {
            float s2 = 0.f;
            for (int s = 0; s < 32; ++s) s2 += Ks[s][tid];
            nacc += s2;
        }
        __syncthreads();
    }
    float* cp = Cpart + ((size_t)bl * TC + tc) * (E * E);
    #pragma unroll
    for (int r = 0; r < 4; ++r) {
        float4 o = {acc[r][0], acc[r][1], acc[r][2], acc[r][3]};
        *(float4*)(cp + (ty * 4 + r) * E + tx * 4) = o;
    }
    if (tid < 64) npart[((size_t)bl * TC + tc) * E + tid] = nacc;
}

// ---------------------------------------------------------------------------
// K5: reduce partials, compute o/q at t=T-1, final h, write h + C to d_out.
// ---------------------------------------------------------------------------
__global__ __launch_bounds__(256) void k_final(const float* __restrict__ x,
        const float* __restrict__ Wml, const float* __restrict__ bml,
        const float* __restrict__ Cpart, const float* __restrict__ npart,
        float* __restrict__ out) {
    __shared__ float Cs[E * E];
    __shared__ float xs[D];
    __shared__ float ns[E];
    __shared__ float os[E];
    __shared__ float qs[E];
    int tid = threadIdx.x;
    int bl = blockIdx.x; int b = bl >> 3, l = bl & 7;
    xs[tid] = x[((size_t)(b * T + (T - 1))) * D + tid];
    const float* cp = Cpart + (size_t)bl * TC * (E * E);
    #pragma unroll
    for (int j = 0; j < 4; ++j) {
        int idx = tid * 16 + j * 4;
        float4 s = {0, 0, 0, 0};
        for (int p = 0; p < TC; ++p) {
            float4 v = *(const float4*)(cp + p * (E * E) + idx);
            s.x += v.x; s.y += v.y; s.z += v.z; s.w += v.w;
        }
        *(float4*)&Cs[idx] = s;
        *(float4*)(out + 4096 + (size_t)bl * (E * E) + idx) = s;
    }
    if (tid < 64) {
        float s = 0.f;
        for (int p = 0; p < TC; ++p) s += npart[((size_t)bl * TC + p) * E + tid];
        ns[tid] = s;
    }
    __syncthreads();
    if (tid < 128) {
        int gate = tid >> 6, e = tid & 63;
        int wrow = gate ? (3 * L + l) : l;
        const float* wp = Wml + (size_t)wrow * D * E + e;
        float s = 0.f;
        for (int kk = 0; kk < D; ++kk) s += xs[kk] * wp[kk * E];
        s += bml[wrow * E + e];
        if (gate) qs[e] = s; else os[e] = s;
    }
    __syncthreads();
    if (tid < 64) {
        int j = tid;
        float hc = 0.f;
        for (int i2 = 0; i2 < E; ++i2) hc += Cs[i2 * E + j] * qs[i2];
        float nq = 0.f;
        for (int i2 = 0; i2 < E; ++i2) nq += ns[i2] * qs[i2];
        float denom = fmaxf(nq, 1.0f);
        float sg = 1.0f / (1.0f + __expf(-os[j]));
        out[bl * E + j] = sg * hc / denom;
    }
}

extern "C" void kernel_launch(void* const* d_in, const int* in_sizes, int n_in,
                              void* d_out, int out_size, void* d_ws, size_t ws_size,
                              hipStream_t stream) {
    const float* x    = (const float*)d_in[0];
    const float* Wml  = (const float*)d_in[1];
    const float* bml  = (const float*)d_in[2];
    const float* Wlin = (const float*)d_in[3];
    const float* blin = (const float*)d_in[4];
    float* out = (float*)d_out;
    float* ws = (float*)d_ws;
    float* ibuf  = ws + OFF_I;
    float* fbuf  = ws + OFF_F;
    float* wbuf  = ws + OFF_W;
    float* Vbuf  = ws + OFF_V;
    float* Kbuf  = ws + OFF_K;
    float* Cpart = ws + OFF_CP;
    float* npart = ws + OFF_NP;

    k_ifproj<<<BT / 32, 256, 0, stream>>>(x, Wlin, blin, ibuf, fbuf);
    k_scan<<<B * L, 256, 0, stream>>>(ibuf, fbuf, wbuf);
    k_vkproj<<<dim3(BT / 64, 16), 256, 0, stream>>>(x, Wml, bml, Vbuf, Kbuf);
    k_cgemm<<<dim3(B * L, TC), 256, 0, stream>>>(Vbuf, Kbuf, wbuf, Cpart, npart);
    k_final<<<B * L, 256, 0, stream>>>(x, Wml, bml, Cpart, npart, out);
}

// Round 2
// 74.375 us; speedup vs baseline: 2.2368x; 2.2368x over previous
//
#include <hip/hip_runtime.h>

#define B 8
#define T 2048
#define D 256
#define L 8
#define E 64
#define BT (B*T)

typedef _Float16 f16;
typedef f16 f16x8 __attribute__((ext_vector_type(8)));
typedef float f32x4 __attribute__((ext_vector_type(4)));

// workspace layout (float offsets)
#define OFF_I   0
#define OFF_F   (OFF_I  + B*L*T)            // fp32 131072
#define OFF_W16 (OFF_F  + B*L*T)            // f16  131072 elems -> 65536 floats
#define OFF_X16 (OFF_W16 + B*L*T/2)         // f16  4194304 elems -> 2097152 floats
#define OFF_WT  (OFF_X16 + B*T*D/2)         // f16  16*64*256 -> 131072 floats
#define OFF_VT  (OFF_WT + 16*E*D/2)         // f16  B*L*E*T -> 4194304 floats
#define OFF_KT  (OFF_VT + B*L*E*T/2)
#define OFF_CP  (OFF_KT + B*L*E*T/2)        // fp32 64*16*65*64

// ---------------------------------------------------------------------------
// K0a: convert x fp32 -> f16
// ---------------------------------------------------------------------------
__global__ __launch_bounds__(256) void k_prep_x(const float* __restrict__ x,
                                                f16* __restrict__ x16) {
    int i = (blockIdx.x * 256 + threadIdx.x) * 8;
    float4 v0 = *(const float4*)(x + i);
    float4 v1 = *(const float4*)(x + i + 4);
    f16x8 o;
    o[0] = (f16)v0.x; o[1] = (f16)v0.y; o[2] = (f16)v0.z; o[3] = (f16)v0.w;
    o[4] = (f16)v1.x; o[5] = (f16)v1.y; o[6] = (f16)v1.z; o[7] = (f16)v1.w;
    *(f16x8*)(x16 + i) = o;
}

// ---------------------------------------------------------------------------
// K0b: transpose v/k weight rows (wrow = 8..23) to Wt16[vkrow][e][d] f16
// ---------------------------------------------------------------------------
__global__ __launch_bounds__(256) void k_prep_w(const float* __restrict__ Wml,
                                                f16* __restrict__ Wt16) {
    __shared__ float ts[64][65];
    int tid = threadIdx.x;
    int vkrow = blockIdx.x;          // 0..15
    int wrow = 8 + vkrow;
    for (int dc = 0; dc < 4; ++dc) {
        int d0 = dc * 64;
        int r = tid >> 2, cq = (tid & 3) * 16;
        const float* src = Wml + ((size_t)wrow * D + d0 + r) * E + cq;
        #pragma unroll
        for (int j = 0; j < 16; j += 4) {
            float4 v = *(const float4*)(src + j);
            ts[r][cq + j] = v.x; ts[r][cq + j + 1] = v.y;
            ts[r][cq + j + 2] = v.z; ts[r][cq + j + 3] = v.w;
        }
        __syncthreads();
        int e = tid >> 2, dq = (tid & 3) * 16;
        f16* dst = Wt16 + ((size_t)vkrow * E + e) * D + d0 + dq;
        f16x8 o0, o1;
        #pragma unroll
        for (int j = 0; j < 8; ++j) {
            o0[j] = (f16)ts[dq + j][e];
            o1[j] = (f16)ts[dq + 8 + j][e];
        }
        *(f16x8*)dst = o0;
        *(f16x8*)(dst + 8) = o1;
        __syncthreads();
    }
}

// ---------------------------------------------------------------------------
// K1: i/f gate projections (fp32, small)
// ---------------------------------------------------------------------------
__global__ __launch_bounds__(256) void k_ifproj(const float* __restrict__ x,
        const float* __restrict__ Wlin, const float* __restrict__ blin,
        float* __restrict__ ibuf, float* __restrict__ fbuf) {
    __shared__ float xs[32][260];
    __shared__ float ws[16][260];
    int tid = threadIdx.x;
    int t0 = blockIdx.x * 32;
    {
        int row = tid >> 3, q = tid & 7;
        const float* src = x + (size_t)(t0 + row) * D + q * 32;
        #pragma unroll
        for (int j = 0; j < 8; ++j) {
            float4 v = *(const float4*)(src + j * 4);
            *(float4*)&xs[row][q * 32 + j * 4] = v;
        }
    }
    {
        int row = tid >> 4, c0 = (tid & 15) * 16;
        const float* src = Wlin + row * D + c0;
        #pragma unroll
        for (int j = 0; j < 4; ++j) {
            float4 v = *(const float4*)(src + j * 4);
            *(float4*)&ws[row][c0 + j * 4] = v;
        }
    }
    __syncthreads();
    int tl = tid >> 4, g = tid & 15;
    float acc0 = 0.f, acc1 = 0.f;
    for (int i = 0; i < D; ++i) {
        float wv = ws[g][i];
        acc0 += xs[tl * 2 + 0][i] * wv;
        acc1 += xs[tl * 2 + 1][i] * wv;
    }
    float bias = blin[g];
    float acc[2] = {acc0 + bias, acc1 + bias};
    #pragma unroll
    for (int u = 0; u < 2; ++u) {
        int t = t0 + tl * 2 + u;
        int b = t >> 11, tt = t & 2047;
        if (g < 8) ibuf[(b * L + g) * T + tt] = acc[u];
        else       fbuf[(b * L + (g - 8)) * T + tt] = acc[u];
    }
}

// ---------------------------------------------------------------------------
// K2: per-(b,l) scan -> w16 (f16)
// ---------------------------------------------------------------------------
__global__ __launch_bounds__(256) void k_scan(const float* __restrict__ ibuf,
        const float* __restrict__ fbuf, f16* __restrict__ w16) {
    __shared__ float part[256];
    __shared__ float red[256];
    int tid = threadIdx.x;
    int base = blockIdx.x * T;
    const float* fp = fbuf + base + tid * 8;
    const float* ip = ibuf + base + tid * 8;
    float4 fa = *(const float4*)fp;
    float4 fb = *(const float4*)(fp + 4);
    float4 ia = *(const float4*)ip;
    float4 ib = *(const float4*)(ip + 4);
    float f[8] = {fa.x, fa.y, fa.z, fa.w, fb.x, fb.y, fb.z, fb.w};
    float iv[8] = {ia.x, ia.y, ia.z, ia.w, ib.x, ib.y, ib.z, ib.w};
    float ls[8]; float run = 0.f;
    #pragma unroll
    for (int r = 0; r < 8; ++r) { run += f[r]; ls[r] = run; }
    part[tid] = run;
    __syncthreads();
    if (tid == 0) {
        float running = 0.f;
        for (int k = 0; k < 256; ++k) { float tmp = part[k]; part[k] = running; running += tmp; }
    }
    __syncthreads();
    float off = part[tid];
    float e[8]; float lmax = -1e30f;
    #pragma unroll
    for (int r = 0; r < 8; ++r) { e[r] = iv[r] - (off + ls[r]); lmax = fmaxf(lmax, e[r]); }
    red[tid] = lmax;
    __syncthreads();
    for (int s = 128; s > 0; s >>= 1) {
        if (tid < s) red[tid] = fmaxf(red[tid], red[tid + s]);
        __syncthreads();
    }
    float M = fmaxf(red[0], 0.0f);
    f16x8 wv8;
    #pragma unroll
    for (int r = 0; r < 8; ++r) wv8[r] = (f16)__expf(e[r] - M);
    *(f16x8*)(w16 + base + tid * 8) = wv8;
}

// ---------------------------------------------------------------------------
// K3: v,k projection via f16 MFMA.  grid (BT/128, 16); by -> (l, vk).
// Output written TRANSPOSED: Vt/Kt[b][l][e][t] f16.
// ---------------------------------------------------------------------------
__global__ __launch_bounds__(256) void k_vkproj_mfma(const f16* __restrict__ x16,
        const f16* __restrict__ Wt16, const float* __restrict__ bml,
        f16* __restrict__ Vt, f16* __restrict__ Kt) {
    __shared__ char lds[24576];
    int tid = threadIdx.x;
    int bx = blockIdx.x, by = blockIdx.y;
    int l = by >> 1, vk = by & 1;
    int vkrow = vk * 8 + l;
    int t0 = bx * 128;
    const f16* xa = x16 + (size_t)t0 * D;
    const f16* wb = Wt16 + (size_t)vkrow * E * D;
    int wv = tid >> 6, lane = tid & 63;
    f32x4 acc[2][4] = {};
    for (int kc = 0; kc < 4; ++kc) {
        int k0 = kc * 64;
        // stage A: 128 rows x 64 k, swizzled
        #pragma unroll
        for (int q = 0; q < 4; ++q) {
            int idx = q * 256 + tid;
            int row = idx >> 3, c = idx & 7;
            f16x8 v = *(const f16x8*)(xa + row * D + k0 + c * 8);
            int ba = row * 128 + c * 16; ba ^= (row & 7) << 4;
            *(f16x8*)(lds + ba) = v;
        }
        // stage B: 64 e-rows x 64 k, swizzled
        #pragma unroll
        for (int q = 0; q < 2; ++q) {
            int idx = q * 256 + tid;
            int e = idx >> 3, c = idx & 7;
            f16x8 v = *(const f16x8*)(wb + e * D + k0 + c * 8);
            int ba = 16384 + e * 128 + c * 16; ba ^= (e & 7) << 4;
            *(f16x8*)(lds + ba) = v;
        }
        __syncthreads();
        #pragma unroll
        for (int kk = 0; kk < 2; ++kk) {
            int ko = kk * 32 + (lane >> 4) * 8;
            f16x8 a[2], bfr[4];
            #pragma unroll
            for (int fr = 0; fr < 2; ++fr) {
                int row = wv * 32 + fr * 16 + (lane & 15);
                int ba = row * 128 + ko * 2; ba ^= (row & 7) << 4;
                a[fr] = *(const f16x8*)(lds + ba);
            }
            #pragma unroll
            for (int fc = 0; fc < 4; ++fc) {
                int e = fc * 16 + (lane & 15);
                int ba = 16384 + e * 128 + ko * 2; ba ^= (e & 7) << 4;
                bfr[fc] = *(const f16x8*)(lds + ba);
            }
            #pragma unroll
            for (int fr = 0; fr < 2; ++fr)
                #pragma unroll
                for (int fc = 0; fc < 4; ++fc)
                    acc[fr][fc] = __builtin_amdgcn_mfma_f32_16x16x32_f16(
                        a[fr], bfr[fc], acc[fr][fc], 0, 0, 0);
        }
        __syncthreads();
    }
    // epilogue: bias + f16 + transpose via LDS -> global (e,t)
    const float* bp = bml + (size_t)(8 + vkrow) * E;
    #pragma unroll
    for (int fr = 0; fr < 2; ++fr) {
        #pragma unroll
        for (int fc = 0; fc < 4; ++fc) {
            int e = fc * 16 + (lane & 15);
            float bias = bp[e];
            int swz = (e & 7) << 4;
            #pragma unroll
            for (int r = 0; r < 4; r += 2) {
                int t = wv * 32 + fr * 16 + (lane >> 4) * 4 + r;
                union { f16 h[2]; unsigned u; } pk;
                pk.h[0] = (f16)(acc[fr][fc][r] + bias);
                pk.h[1] = (f16)(acc[fr][fc][r + 1] + bias);
                int ba = e * 256 + t * 2; ba ^= swz;
                *(unsigned*)(lds + ba) = pk.u;
            }
        }
    }
    __syncthreads();
    f16* obuf = vk ? Kt : Vt;
    int e = tid >> 2, tq = (tid & 3) * 32;
    int b = t0 >> 11, tin = t0 & 2047;
    f16* dst = obuf + (((size_t)(b * L + l) * E + e) * T) + tin + tq;
    int swz = (e & 7) << 4;
    #pragma unroll
    for (int c = 0; c < 4; ++c) {
        int ba = e * 256 + (tq + c * 8) * 2; ba ^= swz;
        f16x8 v = *(const f16x8*)(lds + ba);
        *(f16x8*)(dst + c * 8) = v;
    }
}

// ---------------------------------------------------------------------------
// K4: C = sum_t w_t v_t k_t^T via MFMA.  grid (64, 4): (bl, tchunk).
// Row 64 of each partial = n_j (ones (x) w trick).  4 wave-partials/block.
// ---------------------------------------------------------------------------
__global__ __launch_bounds__(256) void k_cgemm_mfma(const f16* __restrict__ Vt,
        const f16* __restrict__ Kt, const f16* __restrict__ w16,
        float* __restrict__ Cpart) {
    int tid = threadIdx.x;
    int bl = blockIdx.x, tc = blockIdx.y;
    int wv = tid >> 6, lane = tid & 63;
    const f16* vp = Vt + (size_t)bl * E * T;
    const f16* kp = Kt + (size_t)bl * E * T;
    const f16* wp = w16 + (size_t)bl * T;
    f32x4 acc[5][4] = {};
    int tbase = tc * 512 + wv * 128;
    for (int kc = 0; kc < 4; ++kc) {
        int tt = tbase + kc * 32 + (lane >> 4) * 8;
        f16x8 wfrag = *(const f16x8*)(wp + tt);
        f16x8 a[5], bfr[4];
        #pragma unroll
        for (int m = 0; m < 4; ++m) {
            int i = m * 16 + (lane & 15);
            f16x8 v = *(const f16x8*)(vp + (size_t)i * T + tt);
            a[m] = v * wfrag;
        }
        a[4] = wfrag;
        #pragma unroll
        for (int nn = 0; nn < 4; ++nn) {
            int j = nn * 16 + (lane & 15);
            bfr[nn] = *(const f16x8*)(kp + (size_t)j * T + tt);
        }
        #pragma unroll
        for (int m = 0; m < 5; ++m)
            #pragma unroll
            for (int nn = 0; nn < 4; ++nn)
                acc[m][nn] = __builtin_amdgcn_mfma_f32_16x16x32_f16(
                    a[m], bfr[nn], acc[m][nn], 0, 0, 0);
    }
    float* cp = Cpart + ((size_t)bl * 16 + tc * 4 + wv) * (65 * 64);
    #pragma unroll
    for (int m = 0; m < 4; ++m)
        #pragma unroll
        for (int nn = 0; nn < 4; ++nn)
            #pragma unroll
            for (int r = 0; r < 4; ++r) {
                int row = m * 16 + (lane >> 4) * 4 + r;
                cp[row * 64 + nn * 16 + (lane & 15)] = acc[m][nn][r];
            }
    if ((lane >> 4) == 0) {
        #pragma unroll
        for (int nn = 0; nn < 4; ++nn)
            cp[4096 + nn * 16 + (lane & 15)] = acc[4][nn][0];
    }
}

// ---------------------------------------------------------------------------
// K5: reduce 16 partials, compute o/q at t=T-1, final h, write h + C.
// ---------------------------------------------------------------------------
__global__ __launch_bounds__(256) void k_final(const float* __restrict__ x,
        const float* __restrict__ Wml, const float* __restrict__ bml,
        const float* __restrict__ Cpart, float* __restrict__ out) {
    __shared__ float Cs[E * E];
    __shared__ float xs[D];
    __shared__ float ns[E];
    __shared__ float os[E];
    __shared__ float qs[E];
    int tid = threadIdx.x;
    int bl = blockIdx.x; int b = bl >> 3, l = bl & 7;
    xs[tid] = x[((size_t)(b * T + (T - 1))) * D + tid];
    const float* cp = Cpart + (size_t)bl * 16 * (65 * 64);
    #pragma unroll
    for (int j = 0; j < 4; ++j) {
        int idx = tid * 16 + j * 4;
        float4 s = {0, 0, 0, 0};
        for (int p = 0; p < 16; ++p) {
            float4 v = *(const float4*)(cp + p * (65 * 64) + idx);
            s.x += v.x; s.y += v.y; s.z += v.z; s.w += v.w;
        }
        *(float4*)&Cs[idx] = s;
        *(float4*)(out + 4096 + (size_t)bl * (E * E) + idx) = s;
    }
    if (tid < 64) {
        float s = 0.f;
        for (int p = 0; p < 16; ++p) s += cp[p * (65 * 64) + 4096 + tid];
        ns[tid] = s;
    }
    __syncthreads();
    if (tid < 128) {
        int gate = tid >> 6, e = tid & 63;
        int wrow = gate ? (3 * L + l) : l;
        const float* wpp = Wml + (size_t)wrow * D * E + e;
        float s = 0.f;
        for (int kk = 0; kk < D; ++kk) s += xs[kk] * wpp[kk * E];
        s += bml[wrow * E + e];
        if (gate) qs[e] = s; else os[e] = s;
    }
    __syncthreads();
    if (tid < 64) {
        int j = tid;
        float hc = 0.f;
        for (int i2 = 0; i2 < E; ++i2) hc += Cs[i2 * E + j] * qs[i2];
        float nq = 0.f;
        for (int i2 = 0; i2 < E; ++i2) nq += ns[i2] * qs[i2];
        float denom = fmaxf(nq, 1.0f);
        float sg = 1.0f / (1.0f + __expf(-os[j]));
        out[bl * E + j] = sg * hc / denom;
    }
}

extern "C" void kernel_launch(void* const* d_in, const int* in_sizes, int n_in,
                              void* d_out, int out_size, void* d_ws, size_t ws_size,
                              hipStream_t stream) {
    const float* x    = (const float*)d_in[0];
    const float* Wml  = (const float*)d_in[1];
    const float* bml  = (const float*)d_in[2];
    const float* Wlin = (const float*)d_in[3];
    const float* blin = (const float*)d_in[4];
    float* out = (float*)d_out;
    float* ws = (float*)d_ws;
    float* ibuf  = ws + OFF_I;
    float* fbuf  = ws + OFF_F;
    f16*   w16   = (f16*)(ws + OFF_W16);
    f16*   x16   = (f16*)(ws + OFF_X16);
    f16*   Wt16  = (f16*)(ws + OFF_WT);
    f16*   Vt    = (f16*)(ws + OFF_VT);
    f16*   Kt    = (f16*)(ws + OFF_KT);
    float* Cpart = ws + OFF_CP;

    k_prep_x<<<BT * D / (256 * 8), 256, 0, stream>>>(x, x16);
    k_prep_w<<<16, 256, 0, stream>>>(Wml, Wt16);
    k_ifproj<<<BT / 32, 256, 0, stream>>>(x, Wlin, blin, ibuf, fbuf);
    k_scan<<<B * L, 256, 0, stream>>>(ibuf, fbuf, w16);
    k_vkproj_mfma<<<dim3(BT / 128, 16), 256, 0, stream>>>(x16, Wt16, bml, Vt, Kt);
    k_cgemm_mfma<<<dim3(B * L, 4), 256, 0, stream>>>(Vt, Kt, w16, Cpart);
    k_final<<<B * L, 256, 0, stream>>>(x, Wml, bml, Cpart, out);
}